// Round 6
// baseline (750.100 us; speedup 1.0000x reference)
//
#include <hip/hip_runtime.h>

typedef _Float16 f16;
typedef _Float16 h4 __attribute__((ext_vector_type(4)));
typedef _Float16 v8h __attribute__((ext_vector_type(8)));
typedef _Float16 h8 __attribute__((ext_vector_type(8)));
typedef float v4f __attribute__((ext_vector_type(4)));

#define INV_SQRT_C 0.08838834764831845f

// ---------------- weight transforms ----------------
__global__ void wt1_k(const float* __restrict__ w1, f16* __restrict__ wT)
{
  int idx = blockIdx.x * 256 + threadIdx.x;   // 2048
  int k = idx & 31, row = idx >> 5;
  float v = 0.f;
  if (row < 32) {
    int oc = row, q = k >> 3, j = k & 7;
    if (q < 3) v = w1[(oc * 3 + q) * 9 + j];
  } else {
    int oc = row - 32;
    if (k < 3) v = w1[(oc * 3 + k) * 9 + 8];
  }
  wT[idx] = (f16)v;
}

__global__ void wt2_k(const float* __restrict__ w2, f16* __restrict__ wT)
{
  int idx = blockIdx.x * 256 + threadIdx.x;          // 18432
  int ic = idx & 31, oc = (idx >> 5) & 63, khkw = idx >> 11;
  wT[idx] = (f16)w2[(oc * 32 + ic) * 9 + khkw];
}

__global__ void wt3_k(const float* __restrict__ w3, f16* __restrict__ wT)
{
  int idx = blockIdx.x * 256 + threadIdx.x;          // 73728
  int ic5 = idx & 31, oc = (idx >> 5) & 127, ch = idx >> 12;
  int khkw = ch >> 1, ich = ch & 1;
  int ic = ich * 32 + ic5;
  wT[idx] = (f16)w3[(oc * 64 + ic) * 9 + khkw];
}

// ---------------- fused conv1 (MFMA im2col) + conv2 MFMA ----------------
// grid (128 oh, 2 ow-half, 64 bb); bb = img*32 + b. block 256 = 4 waves.
// sA pitch = 40 f16 (80 B = 20 banks): stride-2 conv2 reads rotate 8 banks per
// n15 -> ds_read_b128 spreads over all 32 banks (8 dw/bank, optimal). No XOR
// swizzle needed.
__global__ __launch_bounds__(256, 4) void conv12_m(const float* __restrict__ img_t,
    const float* __restrict__ img_t1,
    const f16* __restrict__ wT1, const float* __restrict__ b1,
    const f16* __restrict__ wT2, const float* __restrict__ b2, f16* __restrict__ out)
{
  const int oh = blockIdx.x, g = blockIdx.y, bb = blockIdx.z;
  const int tid = threadIdx.x;
  const int lane = tid & 63, wv = tid >> 6;
  const int n15 = lane & 15, quad = lane >> 4;

  __shared__ f16 sImgF[5][134][4];
  __shared__ f16 sA[3 * 132 * 40];

  const int OW0 = g * 64;
  const int ibase = 2 * OW0 - 2;
  const int ihb = 2 * oh - 2;
  const float* imgb = (bb < 32 ? img_t : img_t1) + (long)(bb & 31) * 3 * 65536;

  // stage img tile fp16: 15 segments (c,r) x 134 cols, float2-vectorized
  for (int idx = tid; idx < 1005; idx += 256) {
    int seg = idx / 67;              // 0..14
    int p2 = idx - seg * 67;         // 0..66
    int r = seg % 5, c = seg / 5;
    int col = p2 * 2;
    int ih = ihb + r;
    int iw0 = ibase + col;           // even
    f16 v0 = (f16)0.f, v1 = (f16)0.f;
    if ((unsigned)ih < 256u) {
      const float* rp = imgb + c * 65536 + ih * 256;
      if ((unsigned)iw0 < 255u) {
        float2 f2 = *(const float2*)(rp + iw0);
        v0 = (f16)f2.x; v1 = (f16)f2.y;
      } else {
        if ((unsigned)iw0 < 256u) v0 = (f16)rp[iw0];
        if ((unsigned)(iw0 + 1) < 256u) v1 = (f16)rp[iw0 + 1];
      }
    }
    sImgF[r][col][c] = v0;
    sImgF[r][col + 1][c] = v1;
  }
  for (int idx = tid; idx < 670; idx += 256) {
    int col = idx % 134, r = idx / 134;
    sImgF[r][col][3] = (f16)0.f;
  }
  __syncthreads();

  v8h a0 = *(const v8h*)(wT1 + n15 * 32 + quad * 8);
  v8h a1 = *(const v8h*)(wT1 + (16 + n15) * 32 + quad * 8);
  v8h a2 = *(const v8h*)(wT1 + (32 + n15) * 32 + quad * 8);
  v8h a3 = *(const v8h*)(wT1 + (48 + n15) * 32 + quad * 8);
  float4 bb0 = *(const float4*)(b1 + quad * 4);
  float4 bb1 = *(const float4*)(b1 + 16 + quad * 4);

  for (int grp = wv; grp < 25; grp += 4) {
    int p = grp * 16 + n15;
    bool pv = p < 387;
    int pc = pv ? p : 386;
    int yr = pc >= 258 ? 2 : (pc >= 129 ? 1 : 0);
    int ci = pc - yr * 129;
    const f16* sp = &sImgF[yr][ci][0] + quad;
    v8h B1;
    #pragma unroll
    for (int j = 0; j < 8; j++)
      B1[j] = sp[(j / 3) * 536 + (j % 3) * 4];
    h4 t = *(const h4*)(&sImgF[yr + 2][ci + 2][0]);
    v8h B2;
    B2[0] = t[0]; B2[1] = t[1]; B2[2] = t[2]; B2[3] = t[3];
    B2[4] = t[0]; B2[5] = t[1]; B2[6] = t[2]; B2[7] = t[3];
    v4f acc0 = {}, acc1 = {};
    acc0 = __builtin_amdgcn_mfma_f32_16x16x32_f16(a0, B1, acc0, 0, 0, 0);
    acc1 = __builtin_amdgcn_mfma_f32_16x16x32_f16(a1, B1, acc1, 0, 0, 0);
    acc0 = __builtin_amdgcn_mfma_f32_16x16x32_f16(a2, B2, acc0, 0, 0, 0);
    acc1 = __builtin_amdgcn_mfma_f32_16x16x32_f16(a3, B2, acc1, 0, 0, 0);
    int y = 2 * oh - 1 + yr;
    int iw = ibase + 1 + ci;
    bool valid = pv && ((unsigned)y < 256u) && ((unsigned)iw < 256u);
    f16* base = &sA[(yr * 132 + ci) * 40];
    h4 pk0, pk1;
    #pragma unroll
    for (int r = 0; r < 4; r++) {
      float v0 = acc0[r] + ((const float*)&bb0)[r];
      float v1 = acc1[r] + ((const float*)&bb1)[r];
      pk0[r] = (f16)((valid && v0 > 0.f) ? v0 : 0.f);
      pk1[r] = (f16)((valid && v1 > 0.f) ? v1 : 0.f);
    }
    if (pv) {
      *(h4*)(base + quad * 4) = pk0;           // channels quad*4 + r
      *(h4*)(base + 16 + quad * 4) = pk1;      // channels 16 + quad*4 + r
    }
  }
  __syncthreads();

  v4f acc[4] = {};
  for (int kh = 0; kh < 3; kh++) {
    for (int kw = 0; kw < 3; kw++) {
      int khkw = kh * 3 + kw;
      const f16* wp = wT2 + khkw * 2048 + n15 * 32 + quad * 8;
      v8h w0 = *(const v8h*)(wp);
      v8h w1v = *(const v8h*)(wp + 512);
      v8h w2v = *(const v8h*)(wp + 1024);
      v8h w3v = *(const v8h*)(wp + 1536);
      int ci = 32 * wv + 2 * n15 + kw;
      v8h bf = *(const v8h*)&sA[(kh * 132 + ci) * 40 + quad * 8];
      acc[0] = __builtin_amdgcn_mfma_f32_16x16x32_f16(w0, bf, acc[0], 0, 0, 0);
      acc[1] = __builtin_amdgcn_mfma_f32_16x16x32_f16(w1v, bf, acc[1], 0, 0, 0);
      acc[2] = __builtin_amdgcn_mfma_f32_16x16x32_f16(w2v, bf, acc[2], 0, 0, 0);
      acc[3] = __builtin_amdgcn_mfma_f32_16x16x32_f16(w3v, bf, acc[3], 0, 0, 0);
    }
  }
  const int ow = OW0 + wv * 16 + n15;
  #pragma unroll
  for (int mt = 0; mt < 4; mt++) {
    int oc0 = mt * 16 + quad * 4;
    float4 bbv = *(const float4*)(b2 + oc0);
    h4 pk;
    #pragma unroll
    for (int r = 0; r < 4; r++) {
      float v = acc[mt][r] + ((const float*)&bbv)[r];
      pk[r] = (f16)(v > 0.f ? v : 0.f);
    }
    *(h4*)(out + (((long)(bb * 128 + oh) * 128 + ow) * 64) + oc0) = pk;
  }
}

// ---------------- conv3 MFMA v2: 64->128, stride 2, LDS-staged, all 128 oc ----------------
__global__ __launch_bounds__(256, 3) void conv3_m(const f16* __restrict__ in,
    const f16* __restrict__ wT, const float* __restrict__ b3,
    float* __restrict__ zbase, f16* __restrict__ nhbase)
{
  const int oh = blockIdx.x, bb = blockIdx.y;
  const int ib = bb >> 5, b = bb & 31;
  const int tid = threadIdx.x;
  const int lane = tid & 63, wv = tid >> 6;
  const int n15 = lane & 15, quad = lane >> 4;
  const int ow = wv * 16 + n15;

  __shared__ f16 sIn[3 * 128 * 64];

  const f16* inb = in + (long)bb * (128 * 128 * 64);
  const int ih0 = 2 * oh - 1;
  for (int idx = tid; idx < 3072; idx += 256) {
    int ck = idx & 7, iw = (idx >> 3) & 127, r = idx >> 10;
    int ih = ih0 + r;
    h8 v;
    #pragma unroll
    for (int e = 0; e < 8; e++) v[e] = (f16)0.f;
    if ((unsigned)ih < 128u) v = *(const h8*)(inb + ((long)(ih * 128 + iw)) * 64 + ck * 8);
    int sck = ck ^ ((iw >> 1) & 7);
    *(h8*)(&sIn[(r * 128 + iw) * 64 + sck * 8]) = v;
  }
  __syncthreads();

  v4f acc[8] = {};
  for (int kh = 0; kh < 3; kh++) {
    for (int kw = 0; kw < 3; kw++) {
      int iw = 2 * ow + kw - 1;
      bool bok = (unsigned)iw < 128u;
      int iwc = bok ? iw : 0;
      #pragma unroll
      for (int ich = 0; ich < 2; ich++) {
        int ch = (kh * 3 + kw) * 2 + ich;
        int ck = ich * 4 + quad;
        int sck = ck ^ ((iwc >> 1) & 7);
        v8h bf;
        #pragma unroll
        for (int e = 0; e < 8; e++) bf[e] = (f16)0.f;
        if (bok) bf = *(const v8h*)&sIn[(kh * 128 + iwc) * 64 + sck * 8];
        const f16* wp = wT + ((long)(ch * 128 + n15)) * 32 + quad * 8;
        #pragma unroll
        for (int mt = 0; mt < 8; mt++) {
          v8h a = *(const v8h*)(wp + mt * 512);
          acc[mt] = __builtin_amdgcn_mfma_f32_16x16x32_f16(a, bf, acc[mt], 0, 0, 0);
        }
      }
    }
  }

  float* zo = zbase + (long)ib * 16777216L;
  f16* nh = nhbase + (long)ib * 16777216L;
  #pragma unroll
  for (int mt = 0; mt < 8; mt++) {
    int oc0 = mt * 16 + quad * 4;
    float4 bbv = *(const float4*)(b3 + oc0);
    float rv[4];
    #pragma unroll
    for (int r = 0; r < 4; r++) {
      float v = acc[mt][r] + ((const float*)&bbv)[r];
      rv[r] = v > 0.f ? v : 0.f;
    }
    #pragma unroll
    for (int r = 0; r < 4; r++)
      zo[(((long)(b * 128 + oc0 + r) * 64 + oh) * 64) + ow] = rv[r];
    h4 pk;
    #pragma unroll
    for (int r = 0; r < 4; r++) pk[r] = (f16)rv[r];
    *(h4*)(nh + (((long)(b * 64 + oh) * 64 + ow) * 128) + oc0) = pk;
  }
}

// ---------------- local correlation via MFMA: K=13, C=128 ----------------
__global__ __launch_bounds__(256) void corr_m(const f16* __restrict__ zt,
    const f16* __restrict__ zt1, float* __restrict__ corr, float* __restrict__ part)
{
  const int h = blockIdx.x, b = blockIdx.y;
  const int lane = threadIdx.x & 63, wv = threadIdx.x >> 6;
  const int n15 = lane & 15, quad = lane >> 4;
  const int w0 = wv * 16;
  __shared__ float sC[64][17];

  const f16* arow = zt + (((long)(b * 64 + h) * 64 + (w0 + n15)) * 128) + quad * 8;
  v8h A[4];
  #pragma unroll
  for (int ks = 0; ks < 4; ks++) A[ks] = *(const v8h*)(arow + ks * 32);

  float* cb = corr + (long)b * 169 * 4096 + h * 64;

  const int q4r0 = quad * 4;
  const int wq0 = w0 - 6 + n15;
  const int wq1 = w0 + 10 + n15;
  const bool ok0 = (unsigned)wq0 < 64u;
  const bool ok1 = (unsigned)wq1 < 64u;

  for (int ki = 0; ki < 13; ki++) {
    int row = h + ki - 6;
    bool rok = (unsigned)row < 64u;
    v4f acc0 = {}, acc1 = {};
    if (rok) {
      const f16* brow = zt1 + ((long)(b * 64 + row) * 64) * 128;
      const f16* bp0 = brow + (long)wq0 * 128 + quad * 8;
      const f16* bp1 = brow + (long)wq1 * 128 + quad * 8;
      #pragma unroll
      for (int ks = 0; ks < 4; ks++) {
        v8h b0, b1;
        #pragma unroll
        for (int k = 0; k < 8; k++) { b0[k] = (f16)0.f; b1[k] = (f16)0.f; }
        if (ok0) b0 = *(const v8h*)(bp0 + ks * 32);
        if (ok1) b1 = *(const v8h*)(bp1 + ks * 32);
        acc0 = __builtin_amdgcn_mfma_f32_16x16x32_f16(A[ks], b0, acc0, 0, 0, 0);
        acc1 = __builtin_amdgcn_mfma_f32_16x16x32_f16(A[ks], b1, acc1, 0, 0, 0);
      }
    }
    __syncthreads();
    #pragma unroll
    for (int r = 0; r < 4; r++) {
      int q4r = q4r0 + r;
      int w = w0 + q4r;
      int kj0 = n15 - q4r;
      if (kj0 >= 0 && kj0 < 13) sC[w][kj0] = acc0[r] * INV_SQRT_C;
      int kj1 = kj0 + 16;
      if (kj1 < 13) sC[w][kj1] = acc1[r] * INV_SQRT_C;
    }
    __syncthreads();
    for (int idx = threadIdx.x; idx < 832; idx += 256) {
      int w = idx & 63, kj = idx >> 6;
      float v = sC[w][kj];
      cb[(long)(ki * 13 + kj) * 4096 + w] = v;
      #pragma unroll
      for (int off = 32; off > 0; off >>= 1) v += __shfl_down(v, off, 64);
      if (lane == 0) part[(long)(ki * 13 + kj) * 2048 + b * 64 + h] = v;
    }
  }
}

// ---------------- h_t: reduce partial row sums over h ----------------
__global__ __launch_bounds__(256) void ht2_k(const float* __restrict__ part,
                                             float* __restrict__ ht)
{
  int o = blockIdx.x;
  int t = threadIdx.x;
  int b = t >> 3, s = t & 7;
  const float* p = part + (long)o * 2048 + b * 64 + s * 8;
  float v = 0.f;
  #pragma unroll
  for (int i = 0; i < 8; i++) v += p[i];
  #pragma unroll
  for (int off = 4; off > 0; off >>= 1) v += __shfl_down(v, off, 8);
  if (s == 0) ht[b * 169 + o] = v * (1.f / 4096.f);
}

// ---------------- pred ----------------
__global__ void pred_k(const float* __restrict__ ht, const float* __restrict__ wh,
                       const float* __restrict__ bh, float* __restrict__ pred)
{
  int t = threadIdx.x;
  int b = t >> 1, j = t & 1;
  float s = bh[j];
  for (int o = 0; o < 169; o++) s = fmaf(ht[b * 169 + o], wh[j * 169 + o], s);
  pred[b * 2 + j] = s;
}

extern "C" void kernel_launch(void* const* d_in, const int* in_sizes, int n_in,
                              void* d_out, int out_size, void* d_ws, size_t ws_size,
                              hipStream_t stream)
{
  (void)in_sizes; (void)n_in; (void)out_size; (void)ws_size;
  const float* img_t  = (const float*)d_in[0];
  const float* img_t1 = (const float*)d_in[1];
  const float* w1 = (const float*)d_in[2];
  const float* b1 = (const float*)d_in[3];
  const float* w2 = (const float*)d_in[4];
  const float* b2 = (const float*)d_in[5];
  const float* w3 = (const float*)d_in[6];
  const float* b3 = (const float*)d_in[7];
  const float* wh = (const float*)d_in[8];
  const float* bh = (const float*)d_in[9];
  float* out = (float*)d_out;

  // workspace layout
  char* ws = (char*)d_ws;
  f16* bufB = (f16*)ws;                       // conv2 out NHWC, both imgs: 128 MiB
  f16* nhT  = (f16*)(ws + 134217728L);        // z_t NHWC fp16: 32 MiB (z_t1 contiguous after)
  float* part = (float*)(ws + 201326592L);    // 1.38 MiB

  const long OUT_ZT   = 64;
  const long OUT_ZT1  = OUT_ZT + 16777216L;
  const long OUT_CORR = OUT_ZT1 + 16777216L;
  const long OUT_HT   = OUT_CORR + 22151168L;

  // transposed weights live in the (not-yet-written) corr region of d_out;
  // corr_m fully overwrites this region afterwards.
  f16* wT1 = (f16*)(out + OUT_CORR);          // 2048  f16
  f16* wT2 = wT1 + 2048;                      // 18432 f16
  f16* wT3 = wT2 + 18432;                     // 73728 f16

  wt1_k<<<8, 256, 0, stream>>>(w1, wT1);
  wt2_k<<<72, 256, 0, stream>>>(w2, wT2);
  wt3_k<<<288, 256, 0, stream>>>(w3, wT3);

  conv12_m<<<dim3(128, 2, 64), 256, 0, stream>>>(img_t, img_t1, wT1, b1, wT2, b2, bufB);
  conv3_m<<<dim3(64, 64), 256, 0, stream>>>(bufB, wT3, b3, out + OUT_ZT, nhT);
  corr_m<<<dim3(64, 32), 256, 0, stream>>>(nhT, nhT + 16777216L, out + OUT_CORR, part);
  ht2_k<<<169, 256, 0, stream>>>(part, out + OUT_HT);
  pred_k<<<1, 64, 0, stream>>>(out + OUT_HT, wh, bh, out);
}

// Round 7
// 740.678 us; speedup vs baseline: 1.0127x; 1.0127x over previous
//
#include <hip/hip_runtime.h>

typedef _Float16 f16;
typedef _Float16 h4 __attribute__((ext_vector_type(4)));
typedef _Float16 v8h __attribute__((ext_vector_type(8)));
typedef _Float16 h8 __attribute__((ext_vector_type(8)));
typedef float v4f __attribute__((ext_vector_type(4)));

#define INV_SQRT_C 0.08838834764831845f

// ---------------- weight transforms ----------------
__global__ void wt1_k(const float* __restrict__ w1, f16* __restrict__ wT)
{
  int idx = blockIdx.x * 256 + threadIdx.x;   // 2048
  int k = idx & 31, row = idx >> 5;
  float v = 0.f;
  if (row < 32) {
    int oc = row, q = k >> 3, j = k & 7;
    if (q < 3) v = w1[(oc * 3 + q) * 9 + j];
  } else {
    int oc = row - 32;
    if (k < 3) v = w1[(oc * 3 + k) * 9 + 8];
  }
  wT[idx] = (f16)v;
}

__global__ void wt2_k(const float* __restrict__ w2, f16* __restrict__ wT)
{
  int idx = blockIdx.x * 256 + threadIdx.x;          // 18432
  int ic = idx & 31, oc = (idx >> 5) & 63, khkw = idx >> 11;
  wT[idx] = (f16)w2[(oc * 32 + ic) * 9 + khkw];
}

__global__ void wt3_k(const float* __restrict__ w3, f16* __restrict__ wT)
{
  int idx = blockIdx.x * 256 + threadIdx.x;          // 73728
  int ic5 = idx & 31, oc = (idx >> 5) & 127, ch = idx >> 12;
  int khkw = ch >> 1, ich = ch & 1;
  int ic = ich * 32 + ic5;
  wT[idx] = (f16)w3[(oc * 64 + ic) * 9 + khkw];
}

// ---------------- fused conv1 (MFMA im2col) + conv2 MFMA ----------------
// grid (128 oh, 2 ow-half, 64 bb); bb = img*32 + b. block 256 = 4 waves.
// Staging: T14 split (issue all channel loads -> pack+write), one h4 store per
// (r,col) incl. zeroed c=3 lane. sA pitch 40 f16.
__global__ __launch_bounds__(256, 4) void conv12_m(const float* __restrict__ img_t,
    const float* __restrict__ img_t1,
    const f16* __restrict__ wT1, const float* __restrict__ b1,
    const f16* __restrict__ wT2, const float* __restrict__ b2, f16* __restrict__ out)
{
  const int oh = blockIdx.x, g = blockIdx.y, bb = blockIdx.z;
  const int tid = threadIdx.x;
  const int lane = tid & 63, wv = tid >> 6;
  const int n15 = lane & 15, quad = lane >> 4;

  __shared__ f16 sImgF[5][134][4];
  __shared__ f16 sA[3 * 132 * 40];

  const int OW0 = g * 64;
  const int ibase = 2 * OW0 - 2;
  const int ihb = 2 * oh - 2;
  const float* imgb = (bb < 32 ? img_t : img_t1) + (long)(bb & 31) * 3 * 65536;

  // stage: 670 (r,col) pairs; 3 loads each issued first (9 in flight), then write
  {
    float gld[3][3];
    int colA[3], rA[3];
    bool okA[3];
    #pragma unroll
    for (int i = 0; i < 3; i++) {
      int p = tid + i * 256;
      bool pok = p < 670;
      int pc = pok ? p : 0;
      int col = pc % 134, r = pc / 134;
      int ih = ihb + r, iw = ibase + col;
      bool ok = pok && ((unsigned)ih < 256u) && ((unsigned)iw < 256u);
      const float* rp = imgb + ih * 256 + iw;
      gld[i][0] = ok ? rp[0] : 0.f;
      gld[i][1] = ok ? rp[65536] : 0.f;
      gld[i][2] = ok ? rp[131072] : 0.f;
      colA[i] = col; rA[i] = r; okA[i] = pok;
    }
    #pragma unroll
    for (int i = 0; i < 3; i++) {
      if (okA[i]) {
        h4 pk;
        pk[0] = (f16)gld[i][0]; pk[1] = (f16)gld[i][1];
        pk[2] = (f16)gld[i][2]; pk[3] = (f16)0.f;
        *(h4*)(&sImgF[rA[i]][colA[i]][0]) = pk;
      }
    }
  }
  __syncthreads();

  v8h a0 = *(const v8h*)(wT1 + n15 * 32 + quad * 8);
  v8h a1 = *(const v8h*)(wT1 + (16 + n15) * 32 + quad * 8);
  v8h a2 = *(const v8h*)(wT1 + (32 + n15) * 32 + quad * 8);
  v8h a3 = *(const v8h*)(wT1 + (48 + n15) * 32 + quad * 8);
  float4 bb0 = *(const float4*)(b1 + quad * 4);
  float4 bb1 = *(const float4*)(b1 + 16 + quad * 4);

  for (int grp = wv; grp < 25; grp += 4) {
    int p = grp * 16 + n15;
    bool pv = p < 387;
    int pc = pv ? p : 386;
    int yr = pc >= 258 ? 2 : (pc >= 129 ? 1 : 0);
    int ci = pc - yr * 129;
    const f16* sp = &sImgF[yr][ci][0] + quad;
    v8h B1;
    #pragma unroll
    for (int j = 0; j < 8; j++)
      B1[j] = sp[(j / 3) * 536 + (j % 3) * 4];
    h4 t = *(const h4*)(&sImgF[yr + 2][ci + 2][0]);
    v8h B2;
    B2[0] = t[0]; B2[1] = t[1]; B2[2] = t[2]; B2[3] = t[3];
    B2[4] = t[0]; B2[5] = t[1]; B2[6] = t[2]; B2[7] = t[3];
    v4f acc0 = {}, acc1 = {};
    acc0 = __builtin_amdgcn_mfma_f32_16x16x32_f16(a0, B1, acc0, 0, 0, 0);
    acc1 = __builtin_amdgcn_mfma_f32_16x16x32_f16(a1, B1, acc1, 0, 0, 0);
    acc0 = __builtin_amdgcn_mfma_f32_16x16x32_f16(a2, B2, acc0, 0, 0, 0);
    acc1 = __builtin_amdgcn_mfma_f32_16x16x32_f16(a3, B2, acc1, 0, 0, 0);
    int y = 2 * oh - 1 + yr;
    int iw = ibase + 1 + ci;
    bool valid = pv && ((unsigned)y < 256u) && ((unsigned)iw < 256u);
    f16* base = &sA[(yr * 132 + ci) * 40];
    h4 pk0, pk1;
    #pragma unroll
    for (int r = 0; r < 4; r++) {
      float v0 = acc0[r] + ((const float*)&bb0)[r];
      float v1 = acc1[r] + ((const float*)&bb1)[r];
      pk0[r] = (f16)((valid && v0 > 0.f) ? v0 : 0.f);
      pk1[r] = (f16)((valid && v1 > 0.f) ? v1 : 0.f);
    }
    if (pv) {
      *(h4*)(base + quad * 4) = pk0;
      *(h4*)(base + 16 + quad * 4) = pk1;
    }
  }
  __syncthreads();

  v4f acc[4] = {};
  for (int kh = 0; kh < 3; kh++) {
    for (int kw = 0; kw < 3; kw++) {
      int khkw = kh * 3 + kw;
      const f16* wp = wT2 + khkw * 2048 + n15 * 32 + quad * 8;
      v8h w0 = *(const v8h*)(wp);
      v8h w1v = *(const v8h*)(wp + 512);
      v8h w2v = *(const v8h*)(wp + 1024);
      v8h w3v = *(const v8h*)(wp + 1536);
      int ci = 32 * wv + 2 * n15 + kw;
      v8h bf = *(const v8h*)&sA[(kh * 132 + ci) * 40 + quad * 8];
      acc[0] = __builtin_amdgcn_mfma_f32_16x16x32_f16(w0, bf, acc[0], 0, 0, 0);
      acc[1] = __builtin_amdgcn_mfma_f32_16x16x32_f16(w1v, bf, acc[1], 0, 0, 0);
      acc[2] = __builtin_amdgcn_mfma_f32_16x16x32_f16(w2v, bf, acc[2], 0, 0, 0);
      acc[3] = __builtin_amdgcn_mfma_f32_16x16x32_f16(w3v, bf, acc[3], 0, 0, 0);
    }
  }
  const int ow = OW0 + wv * 16 + n15;
  #pragma unroll
  for (int mt = 0; mt < 4; mt++) {
    int oc0 = mt * 16 + quad * 4;
    float4 bbv = *(const float4*)(b2 + oc0);
    h4 pk;
    #pragma unroll
    for (int r = 0; r < 4; r++) {
      float v = acc[mt][r] + ((const float*)&bbv)[r];
      pk[r] = (f16)(v > 0.f ? v : 0.f);
    }
    *(h4*)(out + (((long)(bb * 128 + oh) * 128 + ow) * 64) + oc0) = pk;
  }
}

// ---------------- conv3 MFMA: 64->128, stride 2, LDS-staged, all 128 oc ----------------
// T14 split staging: 12 independent global loads issued first (all in flight),
// then 12 ds_writes. Kills the 12x serial HBM-latency chain.
__global__ __launch_bounds__(256, 3) void conv3_m(const f16* __restrict__ in,
    const f16* __restrict__ wT, const float* __restrict__ b3,
    float* __restrict__ zbase, f16* __restrict__ nhbase)
{
  const int oh = blockIdx.x, bb = blockIdx.y;
  const int ib = bb >> 5, b = bb & 31;
  const int tid = threadIdx.x;
  const int lane = tid & 63, wv = tid >> 6;
  const int n15 = lane & 15, quad = lane >> 4;
  const int ow = wv * 16 + n15;

  __shared__ f16 sIn[3 * 128 * 64];

  const f16* inb = in + (long)bb * (128 * 128 * 64);
  const int ih0 = 2 * oh - 1;

  {
    h8 stg[12];
    #pragma unroll
    for (int i = 0; i < 12; i++) {
      int idx = tid + i * 256;
      int ck = idx & 7, iw = (idx >> 3) & 127, r = idx >> 10;
      int ih = ih0 + r;
      h8 v;
      #pragma unroll
      for (int e = 0; e < 8; e++) v[e] = (f16)0.f;
      if ((unsigned)ih < 128u) v = *(const h8*)(inb + ((long)(ih * 128 + iw)) * 64 + ck * 8);
      stg[i] = v;
    }
    #pragma unroll
    for (int i = 0; i < 12; i++) {
      int idx = tid + i * 256;
      int ck = idx & 7, iw = (idx >> 3) & 127, r = idx >> 10;
      int sck = ck ^ ((iw >> 1) & 7);
      *(h8*)(&sIn[(r * 128 + iw) * 64 + sck * 8]) = stg[i];
    }
  }
  __syncthreads();

  v4f acc[8] = {};
  for (int kh = 0; kh < 3; kh++) {
    for (int kw = 0; kw < 3; kw++) {
      int iw = 2 * ow + kw - 1;
      bool bok = (unsigned)iw < 128u;
      int iwc = bok ? iw : 0;
      #pragma unroll
      for (int ich = 0; ich < 2; ich++) {
        int ch = (kh * 3 + kw) * 2 + ich;
        int ck = ich * 4 + quad;
        int sck = ck ^ ((iwc >> 1) & 7);
        v8h bf;
        #pragma unroll
        for (int e = 0; e < 8; e++) bf[e] = (f16)0.f;
        if (bok) bf = *(const v8h*)&sIn[(kh * 128 + iwc) * 64 + sck * 8];
        const f16* wp = wT + ((long)(ch * 128 + n15)) * 32 + quad * 8;
        #pragma unroll
        for (int mt = 0; mt < 8; mt++) {
          v8h a = *(const v8h*)(wp + mt * 512);
          acc[mt] = __builtin_amdgcn_mfma_f32_16x16x32_f16(a, bf, acc[mt], 0, 0, 0);
        }
      }
    }
  }

  float* zo = zbase + (long)ib * 16777216L;
  f16* nh = nhbase + (long)ib * 16777216L;
  #pragma unroll
  for (int mt = 0; mt < 8; mt++) {
    int oc0 = mt * 16 + quad * 4;
    float4 bbv = *(const float4*)(b3 + oc0);
    float rv[4];
    #pragma unroll
    for (int r = 0; r < 4; r++) {
      float v = acc[mt][r] + ((const float*)&bbv)[r];
      rv[r] = v > 0.f ? v : 0.f;
    }
    #pragma unroll
    for (int r = 0; r < 4; r++)
      zo[(((long)(b * 128 + oc0 + r) * 64 + oh) * 64) + ow] = rv[r];
    h4 pk;
    #pragma unroll
    for (int r = 0; r < 4; r++) pk[r] = (f16)rv[r];
    *(h4*)(nh + (((long)(b * 64 + oh) * 64 + ow) * 128) + oc0) = pk;
  }
}

// ---------------- local correlation via MFMA: K=13, C=128 ----------------
__global__ __launch_bounds__(256) void corr_m(const f16* __restrict__ zt,
    const f16* __restrict__ zt1, float* __restrict__ corr, float* __restrict__ part)
{
  const int h = blockIdx.x, b = blockIdx.y;
  const int lane = threadIdx.x & 63, wv = threadIdx.x >> 6;
  const int n15 = lane & 15, quad = lane >> 4;
  const int w0 = wv * 16;
  __shared__ float sC[64][17];

  const f16* arow = zt + (((long)(b * 64 + h) * 64 + (w0 + n15)) * 128) + quad * 8;
  v8h A[4];
  #pragma unroll
  for (int ks = 0; ks < 4; ks++) A[ks] = *(const v8h*)(arow + ks * 32);

  float* cb = corr + (long)b * 169 * 4096 + h * 64;

  const int q4r0 = quad * 4;
  const int wq0 = w0 - 6 + n15;
  const int wq1 = w0 + 10 + n15;
  const bool ok0 = (unsigned)wq0 < 64u;
  const bool ok1 = (unsigned)wq1 < 64u;

  for (int ki = 0; ki < 13; ki++) {
    int row = h + ki - 6;
    bool rok = (unsigned)row < 64u;
    v4f acc0 = {}, acc1 = {};
    if (rok) {
      const f16* brow = zt1 + ((long)(b * 64 + row) * 64) * 128;
      const f16* bp0 = brow + (long)wq0 * 128 + quad * 8;
      const f16* bp1 = brow + (long)wq1 * 128 + quad * 8;
      #pragma unroll
      for (int ks = 0; ks < 4; ks++) {
        v8h b0, b1;
        #pragma unroll
        for (int k = 0; k < 8; k++) { b0[k] = (f16)0.f; b1[k] = (f16)0.f; }
        if (ok0) b0 = *(const v8h*)(bp0 + ks * 32);
        if (ok1) b1 = *(const v8h*)(bp1 + ks * 32);
        acc0 = __builtin_amdgcn_mfma_f32_16x16x32_f16(A[ks], b0, acc0, 0, 0, 0);
        acc1 = __builtin_amdgcn_mfma_f32_16x16x32_f16(A[ks], b1, acc1, 0, 0, 0);
      }
    }
    __syncthreads();
    #pragma unroll
    for (int r = 0; r < 4; r++) {
      int q4r = q4r0 + r;
      int w = w0 + q4r;
      int kj0 = n15 - q4r;
      if (kj0 >= 0 && kj0 < 13) sC[w][kj0] = acc0[r] * INV_SQRT_C;
      int kj1 = kj0 + 16;
      if (kj1 < 13) sC[w][kj1] = acc1[r] * INV_SQRT_C;
    }
    __syncthreads();
    for (int idx = threadIdx.x; idx < 832; idx += 256) {
      int w = idx & 63, kj = idx >> 6;
      float v = sC[w][kj];
      cb[(long)(ki * 13 + kj) * 4096 + w] = v;
      #pragma unroll
      for (int off = 32; off > 0; off >>= 1) v += __shfl_down(v, off, 64);
      if (lane == 0) part[(long)(ki * 13 + kj) * 2048 + b * 64 + h] = v;
    }
  }
}

// ---------------- h_t: reduce partial row sums over h ----------------
__global__ __launch_bounds__(256) void ht2_k(const float* __restrict__ part,
                                             float* __restrict__ ht)
{
  int o = blockIdx.x;
  int t = threadIdx.x;
  int b = t >> 3, s = t & 7;
  const float* p = part + (long)o * 2048 + b * 64 + s * 8;
  float v = 0.f;
  #pragma unroll
  for (int i = 0; i < 8; i++) v += p[i];
  #pragma unroll
  for (int off = 4; off > 0; off >>= 1) v += __shfl_down(v, off, 8);
  if (s == 0) ht[b * 169 + o] = v * (1.f / 4096.f);
}

// ---------------- pred ----------------
__global__ void pred_k(const float* __restrict__ ht, const float* __restrict__ wh,
                       const float* __restrict__ bh, float* __restrict__ pred)
{
  int t = threadIdx.x;
  int b = t >> 1, j = t & 1;
  float s = bh[j];
  for (int o = 0; o < 169; o++) s = fmaf(ht[b * 169 + o], wh[j * 169 + o], s);
  pred[b * 2 + j] = s;
}

extern "C" void kernel_launch(void* const* d_in, const int* in_sizes, int n_in,
                              void* d_out, int out_size, void* d_ws, size_t ws_size,
                              hipStream_t stream)
{
  (void)in_sizes; (void)n_in; (void)out_size; (void)ws_size;
  const float* img_t  = (const float*)d_in[0];
  const float* img_t1 = (const float*)d_in[1];
  const float* w1 = (const float*)d_in[2];
  const float* b1 = (const float*)d_in[3];
  const float* w2 = (const float*)d_in[4];
  const float* b2 = (const float*)d_in[5];
  const float* w3 = (const float*)d_in[6];
  const float* b3 = (const float*)d_in[7];
  const float* wh = (const float*)d_in[8];
  const float* bh = (const float*)d_in[9];
  float* out = (float*)d_out;

  // workspace layout
  char* ws = (char*)d_ws;
  f16* bufB = (f16*)ws;                       // conv2 out NHWC, both imgs: 128 MiB
  f16* nhT  = (f16*)(ws + 134217728L);        // z_t NHWC fp16: 32 MiB (z_t1 contiguous after)
  float* part = (float*)(ws + 201326592L);    // 1.38 MiB

  const long OUT_ZT   = 64;
  const long OUT_ZT1  = OUT_ZT + 16777216L;
  const long OUT_CORR = OUT_ZT1 + 16777216L;
  const long OUT_HT   = OUT_CORR + 22151168L;

  // transposed weights live in the (not-yet-written) corr region of d_out;
  // corr_m fully overwrites this region afterwards.
  f16* wT1 = (f16*)(out + OUT_CORR);          // 2048  f16
  f16* wT2 = wT1 + 2048;                      // 18432 f16
  f16* wT3 = wT2 + 18432;                     // 73728 f16

  wt1_k<<<8, 256, 0, stream>>>(w1, wT1);
  wt2_k<<<72, 256, 0, stream>>>(w2, wT2);
  wt3_k<<<288, 256, 0, stream>>>(w3, wT3);

  conv12_m<<<dim3(128, 2, 64), 256, 0, stream>>>(img_t, img_t1, wT1, b1, wT2, b2, bufB);
  conv3_m<<<dim3(64, 64), 256, 0, stream>>>(bufB, wT3, b3, out + OUT_ZT, nhT);
  corr_m<<<dim3(64, 32), 256, 0, stream>>>(nhT, nhT + 16777216L, out + OUT_CORR, part);
  ht2_k<<<169, 256, 0, stream>>>(part, out + OUT_HT);
  pred_k<<<1, 64, 0, stream>>>(out + OUT_HT, wh, bh, out);
}

// Round 8
// 681.301 us; speedup vs baseline: 1.1010x; 1.0872x over previous
//
#include <hip/hip_runtime.h>

typedef _Float16 f16;
typedef _Float16 h4 __attribute__((ext_vector_type(4)));
typedef _Float16 v8h __attribute__((ext_vector_type(8)));
typedef _Float16 h8 __attribute__((ext_vector_type(8)));
typedef float v4f __attribute__((ext_vector_type(4)));

#define INV_SQRT_C 0.08838834764831845f

// ---------------- weight transforms ----------------
__global__ void wt1_k(const float* __restrict__ w1, f16* __restrict__ wT)
{
  int idx = blockIdx.x * 256 + threadIdx.x;   // 2048
  int k = idx & 31, row = idx >> 5;
  float v = 0.f;
  if (row < 32) {
    int oc = row, q = k >> 3, j = k & 7;
    if (q < 3) v = w1[(oc * 3 + q) * 9 + j];
  } else {
    int oc = row - 32;
    if (k < 3) v = w1[(oc * 3 + k) * 9 + 8];
  }
  wT[idx] = (f16)v;
}

__global__ void wt2_k(const float* __restrict__ w2, f16* __restrict__ wT)
{
  int idx = blockIdx.x * 256 + threadIdx.x;          // 18432
  int ic = idx & 31, oc = (idx >> 5) & 63, khkw = idx >> 11;
  wT[idx] = (f16)w2[(oc * 32 + ic) * 9 + khkw];
}

__global__ void wt3_k(const float* __restrict__ w3, f16* __restrict__ wT)
{
  int idx = blockIdx.x * 256 + threadIdx.x;          // 73728
  int ic5 = idx & 31, oc = (idx >> 5) & 127, ch = idx >> 12;
  int khkw = ch >> 1, ich = ch & 1;
  int ic = ich * 32 + ic5;
  wT[idx] = (f16)w3[(oc * 64 + ic) * 9 + khkw];
}

// ---------------- fused conv1 (MFMA im2col) + conv2 MFMA, persistent over 8 oh ----------------
// grid (16 oh-chunks, 2 ow-half, 64 bb); block 256 = 4 waves; 8 oh rows per block.
// Pipeline per iter: issue stage(oh+1) -> barrier -> conv1(sImg[cur])->sA ->
// barrier -> conv2(sA)->out -> write stage(sImg[cur^1]). Stage latency hides
// under conv1+conv2; weights/bias/meta amortize over 8 rows.
#define STAGE_ISSUE(OH)                                                     \
  {                                                                         \
    int ihb_ = 2 * (OH) - 2;                                                \
    _Pragma("unroll")                                                       \
    for (int i = 0; i < 3; i++) {                                           \
      int ih = ihb_ + rS[i], iw = ibase + colS[i];                          \
      bool ok = pokS[i] && ((unsigned)ih < 256u) && ((unsigned)iw < 256u);  \
      const float* rp = imgb + ih * 256 + iw;                               \
      g0[i] = ok ? rp[0] : 0.f;                                             \
      g1[i] = ok ? rp[65536] : 0.f;                                         \
      g2[i] = ok ? rp[131072] : 0.f;                                        \
    }                                                                       \
  }

#define STAGE_WRITE(BUF)                                                    \
  {                                                                         \
    _Pragma("unroll")                                                       \
    for (int i = 0; i < 3; i++) {                                           \
      if (pokS[i]) {                                                        \
        h4 pk;                                                              \
        pk[0] = (f16)g0[i]; pk[1] = (f16)g1[i];                             \
        pk[2] = (f16)g2[i]; pk[3] = (f16)0.f;                               \
        *(h4*)(&sImgF[BUF][rS[i]][colS[i]][0]) = pk;                        \
      }                                                                     \
    }                                                                       \
  }

__global__ __launch_bounds__(256, 4) void conv12_m(const float* __restrict__ img_t,
    const float* __restrict__ img_t1,
    const f16* __restrict__ wT1, const float* __restrict__ b1,
    const f16* __restrict__ wT2, const float* __restrict__ b2, f16* __restrict__ out)
{
  const int ohc = blockIdx.x, g = blockIdx.y, bb = blockIdx.z;
  const int tid = threadIdx.x;
  const int lane = tid & 63, wv = tid >> 6;
  const int n15 = lane & 15, quad = lane >> 4;

  __shared__ f16 sImgF[2][5][134][4];
  __shared__ f16 sA[3 * 132 * 40];

  const int OW0 = g * 64;
  const int ibase = 2 * OW0 - 2;
  const float* imgb = (bb < 32 ? img_t : img_t1) + (long)(bb & 31) * 3 * 65536;

  // per-thread staging metadata (loop-invariant)
  int colS[3], rS[3]; bool pokS[3];
  #pragma unroll
  for (int i = 0; i < 3; i++) {
    int p = tid + i * 256;
    pokS[i] = p < 670;
    int pc = pokS[i] ? p : 0;
    colS[i] = pc % 134; rS[i] = pc / 134;
  }

  // hoisted conv1 weights + biases
  v8h a0 = *(const v8h*)(wT1 + n15 * 32 + quad * 8);
  v8h a1 = *(const v8h*)(wT1 + (16 + n15) * 32 + quad * 8);
  v8h a2 = *(const v8h*)(wT1 + (32 + n15) * 32 + quad * 8);
  v8h a3 = *(const v8h*)(wT1 + (48 + n15) * 32 + quad * 8);
  float4 bb0 = *(const float4*)(b1 + quad * 4);
  float4 bb1 = *(const float4*)(b1 + 16 + quad * 4);

  float g0[3], g1[3], g2[3];
  const int oh0 = ohc * 8;

  // prologue: stage oh0 into buf 0
  STAGE_ISSUE(oh0);
  STAGE_WRITE(0);

  for (int it = 0; it < 8; it++) {
    const int oh = oh0 + it;
    const int cur = it & 1;
    if (it < 7) STAGE_ISSUE(oh + 1);
    __syncthreads();   // sImg[cur] visible; sA free (prev conv2 done)

    // ---- conv1 phase: sImgF[cur] -> sA ----
    for (int grp = wv; grp < 25; grp += 4) {
      int p = grp * 16 + n15;
      bool pv = p < 387;
      int pc = pv ? p : 386;
      int yr = pc >= 258 ? 2 : (pc >= 129 ? 1 : 0);
      int ci = pc - yr * 129;
      const f16* sp = &sImgF[cur][yr][ci][0] + quad;
      v8h B1;
      #pragma unroll
      for (int j = 0; j < 8; j++)
        B1[j] = sp[(j / 3) * 536 + (j % 3) * 4];
      h4 t = *(const h4*)(&sImgF[cur][yr + 2][ci + 2][0]);
      v8h B2;
      B2[0] = t[0]; B2[1] = t[1]; B2[2] = t[2]; B2[3] = t[3];
      B2[4] = t[0]; B2[5] = t[1]; B2[6] = t[2]; B2[7] = t[3];
      v4f acc0 = {}, acc1 = {};
      acc0 = __builtin_amdgcn_mfma_f32_16x16x32_f16(a0, B1, acc0, 0, 0, 0);
      acc1 = __builtin_amdgcn_mfma_f32_16x16x32_f16(a1, B1, acc1, 0, 0, 0);
      acc0 = __builtin_amdgcn_mfma_f32_16x16x32_f16(a2, B2, acc0, 0, 0, 0);
      acc1 = __builtin_amdgcn_mfma_f32_16x16x32_f16(a3, B2, acc1, 0, 0, 0);
      int y = 2 * oh - 1 + yr;
      int iw = ibase + 1 + ci;
      bool valid = pv && ((unsigned)y < 256u) && ((unsigned)iw < 256u);
      f16* base = &sA[(yr * 132 + ci) * 40];
      h4 pk0, pk1;
      #pragma unroll
      for (int r = 0; r < 4; r++) {
        float v0 = acc0[r] + ((const float*)&bb0)[r];
        float v1 = acc1[r] + ((const float*)&bb1)[r];
        pk0[r] = (f16)((valid && v0 > 0.f) ? v0 : 0.f);
        pk1[r] = (f16)((valid && v1 > 0.f) ? v1 : 0.f);
      }
      if (pv) {
        *(h4*)(base + quad * 4) = pk0;
        *(h4*)(base + 16 + quad * 4) = pk1;
      }
    }
    __syncthreads();

    // ---- conv2 phase: sA -> out ----
    v4f acc[4] = {};
    for (int kh = 0; kh < 3; kh++) {
      for (int kw = 0; kw < 3; kw++) {
        int khkw = kh * 3 + kw;
        const f16* wp = wT2 + khkw * 2048 + n15 * 32 + quad * 8;
        v8h w0 = *(const v8h*)(wp);
        v8h w1v = *(const v8h*)(wp + 512);
        v8h w2v = *(const v8h*)(wp + 1024);
        v8h w3v = *(const v8h*)(wp + 1536);
        int ci = 32 * wv + 2 * n15 + kw;
        v8h bf = *(const v8h*)&sA[(kh * 132 + ci) * 40 + quad * 8];
        acc[0] = __builtin_amdgcn_mfma_f32_16x16x32_f16(w0, bf, acc[0], 0, 0, 0);
        acc[1] = __builtin_amdgcn_mfma_f32_16x16x32_f16(w1v, bf, acc[1], 0, 0, 0);
        acc[2] = __builtin_amdgcn_mfma_f32_16x16x32_f16(w2v, bf, acc[2], 0, 0, 0);
        acc[3] = __builtin_amdgcn_mfma_f32_16x16x32_f16(w3v, bf, acc[3], 0, 0, 0);
      }
    }
    const int ow = OW0 + wv * 16 + n15;
    #pragma unroll
    for (int mt = 0; mt < 4; mt++) {
      int oc0 = mt * 16 + quad * 4;
      float4 bbv = *(const float4*)(b2 + oc0);
      h4 pk;
      #pragma unroll
      for (int r = 0; r < 4; r++) {
        float v = acc[mt][r] + ((const float*)&bbv)[r];
        pk[r] = (f16)(v > 0.f ? v : 0.f);
      }
      *(h4*)(out + (((long)(bb * 128 + oh) * 128 + ow) * 64) + oc0) = pk;
    }

    // ---- write next stage into idle buffer (read next iter after barrier) ----
    if (it < 7) STAGE_WRITE(cur ^ 1);
  }
}

// ---------------- conv3 MFMA: 64->128, stride 2, LDS-staged, all 128 oc ----------------
// T14 split staging: 12 independent global loads issued first, then 12 ds_writes.
__global__ __launch_bounds__(256, 3) void conv3_m(const f16* __restrict__ in,
    const f16* __restrict__ wT, const float* __restrict__ b3,
    float* __restrict__ zbase, f16* __restrict__ nhbase)
{
  const int oh = blockIdx.x, bb = blockIdx.y;
  const int ib = bb >> 5, b = bb & 31;
  const int tid = threadIdx.x;
  const int lane = tid & 63, wv = tid >> 6;
  const int n15 = lane & 15, quad = lane >> 4;
  const int ow = wv * 16 + n15;

  __shared__ f16 sIn[3 * 128 * 64];

  const f16* inb = in + (long)bb * (128 * 128 * 64);
  const int ih0 = 2 * oh - 1;

  {
    h8 stg[12];
    #pragma unroll
    for (int i = 0; i < 12; i++) {
      int idx = tid + i * 256;
      int ck = idx & 7, iw = (idx >> 3) & 127, r = idx >> 10;
      int ih = ih0 + r;
      h8 v;
      #pragma unroll
      for (int e = 0; e < 8; e++) v[e] = (f16)0.f;
      if ((unsigned)ih < 128u) v = *(const h8*)(inb + ((long)(ih * 128 + iw)) * 64 + ck * 8);
      stg[i] = v;
    }
    #pragma unroll
    for (int i = 0; i < 12; i++) {
      int idx = tid + i * 256;
      int ck = idx & 7, iw = (idx >> 3) & 127, r = idx >> 10;
      int sck = ck ^ ((iw >> 1) & 7);
      *(h8*)(&sIn[(r * 128 + iw) * 64 + sck * 8]) = stg[i];
    }
  }
  __syncthreads();

  v4f acc[8] = {};
  for (int kh = 0; kh < 3; kh++) {
    for (int kw = 0; kw < 3; kw++) {
      int iw = 2 * ow + kw - 1;
      bool bok = (unsigned)iw < 128u;
      int iwc = bok ? iw : 0;
      #pragma unroll
      for (int ich = 0; ich < 2; ich++) {
        int ch = (kh * 3 + kw) * 2 + ich;
        int ck = ich * 4 + quad;
        int sck = ck ^ ((iwc >> 1) & 7);
        v8h bf;
        #pragma unroll
        for (int e = 0; e < 8; e++) bf[e] = (f16)0.f;
        if (bok) bf = *(const v8h*)&sIn[(kh * 128 + iwc) * 64 + sck * 8];
        const f16* wp = wT + ((long)(ch * 128 + n15)) * 32 + quad * 8;
        #pragma unroll
        for (int mt = 0; mt < 8; mt++) {
          v8h a = *(const v8h*)(wp + mt * 512);
          acc[mt] = __builtin_amdgcn_mfma_f32_16x16x32_f16(a, bf, acc[mt], 0, 0, 0);
        }
      }
    }
  }

  float* zo = zbase + (long)ib * 16777216L;
  f16* nh = nhbase + (long)ib * 16777216L;
  #pragma unroll
  for (int mt = 0; mt < 8; mt++) {
    int oc0 = mt * 16 + quad * 4;
    float4 bbv = *(const float4*)(b3 + oc0);
    float rv[4];
    #pragma unroll
    for (int r = 0; r < 4; r++) {
      float v = acc[mt][r] + ((const float*)&bbv)[r];
      rv[r] = v > 0.f ? v : 0.f;
    }
    #pragma unroll
    for (int r = 0; r < 4; r++)
      zo[(((long)(b * 128 + oc0 + r) * 64 + oh) * 64) + ow] = rv[r];
    h4 pk;
    #pragma unroll
    for (int r = 0; r < 4; r++) pk[r] = (f16)rv[r];
    *(h4*)(nh + (((long)(b * 64 + oh) * 64 + ow) * 128) + oc0) = pk;
  }
}

// ---------------- local correlation via MFMA: K=13, C=128 ----------------
__global__ __launch_bounds__(256) void corr_m(const f16* __restrict__ zt,
    const f16* __restrict__ zt1, float* __restrict__ corr, float* __restrict__ part)
{
  const int h = blockIdx.x, b = blockIdx.y;
  const int lane = threadIdx.x & 63, wv = threadIdx.x >> 6;
  const int n15 = lane & 15, quad = lane >> 4;
  const int w0 = wv * 16;
  __shared__ float sC[64][17];

  const f16* arow = zt + (((long)(b * 64 + h) * 64 + (w0 + n15)) * 128) + quad * 8;
  v8h A[4];
  #pragma unroll
  for (int ks = 0; ks < 4; ks++) A[ks] = *(const v8h*)(arow + ks * 32);

  float* cb = corr + (long)b * 169 * 4096 + h * 64;

  const int q4r0 = quad * 4;
  const int wq0 = w0 - 6 + n15;
  const int wq1 = w0 + 10 + n15;
  const bool ok0 = (unsigned)wq0 < 64u;
  const bool ok1 = (unsigned)wq1 < 64u;

  for (int ki = 0; ki < 13; ki++) {
    int row = h + ki - 6;
    bool rok = (unsigned)row < 64u;
    v4f acc0 = {}, acc1 = {};
    if (rok) {
      const f16* brow = zt1 + ((long)(b * 64 + row) * 64) * 128;
      const f16* bp0 = brow + (long)wq0 * 128 + quad * 8;
      const f16* bp1 = brow + (long)wq1 * 128 + quad * 8;
      #pragma unroll
      for (int ks = 0; ks < 4; ks++) {
        v8h b0, b1;
        #pragma unroll
        for (int k = 0; k < 8; k++) { b0[k] = (f16)0.f; b1[k] = (f16)0.f; }
        if (ok0) b0 = *(const v8h*)(bp0 + ks * 32);
        if (ok1) b1 = *(const v8h*)(bp1 + ks * 32);
        acc0 = __builtin_amdgcn_mfma_f32_16x16x32_f16(A[ks], b0, acc0, 0, 0, 0);
        acc1 = __builtin_amdgcn_mfma_f32_16x16x32_f16(A[ks], b1, acc1, 0, 0, 0);
      }
    }
    __syncthreads();
    #pragma unroll
    for (int r = 0; r < 4; r++) {
      int q4r = q4r0 + r;
      int w = w0 + q4r;
      int kj0 = n15 - q4r;
      if (kj0 >= 0 && kj0 < 13) sC[w][kj0] = acc0[r] * INV_SQRT_C;
      int kj1 = kj0 + 16;
      if (kj1 < 13) sC[w][kj1] = acc1[r] * INV_SQRT_C;
    }
    __syncthreads();
    for (int idx = threadIdx.x; idx < 832; idx += 256) {
      int w = idx & 63, kj = idx >> 6;
      float v = sC[w][kj];
      cb[(long)(ki * 13 + kj) * 4096 + w] = v;
      #pragma unroll
      for (int off = 32; off > 0; off >>= 1) v += __shfl_down(v, off, 64);
      if (lane == 0) part[(long)(ki * 13 + kj) * 2048 + b * 64 + h] = v;
    }
  }
}

// ---------------- h_t: reduce partial row sums over h ----------------
__global__ __launch_bounds__(256) void ht2_k(const float* __restrict__ part,
                                             float* __restrict__ ht)
{
  int o = blockIdx.x;
  int t = threadIdx.x;
  int b = t >> 3, s = t & 7;
  const float* p = part + (long)o * 2048 + b * 64 + s * 8;
  float v = 0.f;
  #pragma unroll
  for (int i = 0; i < 8; i++) v += p[i];
  #pragma unroll
  for (int off = 4; off > 0; off >>= 1) v += __shfl_down(v, off, 8);
  if (s == 0) ht[b * 169 + o] = v * (1.f / 4096.f);
}

// ---------------- pred ----------------
__global__ void pred_k(const float* __restrict__ ht, const float* __restrict__ wh,
                       const float* __restrict__ bh, float* __restrict__ pred)
{
  int t = threadIdx.x;
  int b = t >> 1, j = t & 1;
  float s = bh[j];
  for (int o = 0; o < 169; o++) s = fmaf(ht[b * 169 + o], wh[j * 169 + o], s);
  pred[b * 2 + j] = s;
}

extern "C" void kernel_launch(void* const* d_in, const int* in_sizes, int n_in,
                              void* d_out, int out_size, void* d_ws, size_t ws_size,
                              hipStream_t stream)
{
  (void)in_sizes; (void)n_in; (void)out_size; (void)ws_size;
  const float* img_t  = (const float*)d_in[0];
  const float* img_t1 = (const float*)d_in[1];
  const float* w1 = (const float*)d_in[2];
  const float* b1 = (const float*)d_in[3];
  const float* w2 = (const float*)d_in[4];
  const float* b2 = (const float*)d_in[5];
  const float* w3 = (const float*)d_in[6];
  const float* b3 = (const float*)d_in[7];
  const float* wh = (const float*)d_in[8];
  const float* bh = (const float*)d_in[9];
  float* out = (float*)d_out;

  // workspace layout
  char* ws = (char*)d_ws;
  f16* bufB = (f16*)ws;                       // conv2 out NHWC, both imgs: 128 MiB
  f16* nhT  = (f16*)(ws + 134217728L);        // z_t NHWC fp16: 32 MiB (z_t1 contiguous after)
  float* part = (float*)(ws + 201326592L);    // 1.38 MiB

  const long OUT_ZT   = 64;
  const long OUT_ZT1  = OUT_ZT + 16777216L;
  const long OUT_CORR = OUT_ZT1 + 16777216L;
  const long OUT_HT   = OUT_CORR + 22151168L;

  // transposed weights live in the (not-yet-written) corr region of d_out;
  // corr_m fully overwrites this region afterwards.
  f16* wT1 = (f16*)(out + OUT_CORR);          // 2048  f16
  f16* wT2 = wT1 + 2048;                      // 18432 f16
  f16* wT3 = wT2 + 18432;                     // 73728 f16

  wt1_k<<<8, 256, 0, stream>>>(w1, wT1);
  wt2_k<<<72, 256, 0, stream>>>(w2, wT2);
  wt3_k<<<288, 256, 0, stream>>>(w3, wT3);

  conv12_m<<<dim3(16, 2, 64), 256, 0, stream>>>(img_t, img_t1, wT1, b1, wT2, b2, bufB);
  conv3_m<<<dim3(64, 64), 256, 0, stream>>>(bufB, wT3, b3, out + OUT_ZT, nhT);
  corr_m<<<dim3(64, 32), 256, 0, stream>>>(nhT, nhT + 16777216L, out + OUT_CORR, part);
  ht2_k<<<169, 256, 0, stream>>>(part, out + OUT_HT);
  pred_k<<<1, 64, 0, stream>>>(out + OUT_HT, wh, bh, out);
}

// Round 9
// 600.344 us; speedup vs baseline: 1.2495x; 1.1348x over previous
//
#include <hip/hip_runtime.h>

typedef _Float16 f16;
typedef _Float16 h4 __attribute__((ext_vector_type(4)));
typedef _Float16 v8h __attribute__((ext_vector_type(8)));
typedef _Float16 h8 __attribute__((ext_vector_type(8)));
typedef float v4f __attribute__((ext_vector_type(4)));

#define INV_SQRT_C 0.08838834764831845f

// ---------------- weight transforms ----------------
__global__ void wt1_k(const float* __restrict__ w1, f16* __restrict__ wT)
{
  int idx = blockIdx.x * 256 + threadIdx.x;   // 2048
  int k = idx & 31, row = idx >> 5;
  float v = 0.f;
  if (row < 32) {
    int oc = row, q = k >> 3, j = k & 7;
    if (q < 3) v = w1[(oc * 3 + q) * 9 + j];
  } else {
    int oc = row - 32;
    if (k < 3) v = w1[(oc * 3 + k) * 9 + 8];
  }
  wT[idx] = (f16)v;
}

__global__ void wt2_k(const float* __restrict__ w2, f16* __restrict__ wT)
{
  int idx = blockIdx.x * 256 + threadIdx.x;          // 18432
  int ic = idx & 31, oc = (idx >> 5) & 63, khkw = idx >> 11;
  wT[idx] = (f16)w2[(oc * 32 + ic) * 9 + khkw];
}

__global__ void wt3_k(const float* __restrict__ w3, f16* __restrict__ wT)
{
  int idx = blockIdx.x * 256 + threadIdx.x;          // 73728
  int ic5 = idx & 31, oc = (idx >> 5) & 127, ch = idx >> 12;
  int khkw = ch >> 1, ich = ch & 1;
  int ic = ich * 32 + ic5;
  wT[idx] = (f16)w3[(oc * 64 + ic) * 9 + khkw];
}

// ---------------- fused conv1 (MFMA im2col) + conv2 MFMA, persistent over 8 oh ----------------
#define STAGE_ISSUE(OH)                                                     \
  {                                                                         \
    int ihb_ = 2 * (OH) - 2;                                                \
    _Pragma("unroll")                                                       \
    for (int i = 0; i < 3; i++) {                                           \
      int ih = ihb_ + rS[i], iw = ibase + colS[i];                          \
      bool ok = pokS[i] && ((unsigned)ih < 256u) && ((unsigned)iw < 256u);  \
      const float* rp = imgb + ih * 256 + iw;                               \
      g0[i] = ok ? rp[0] : 0.f;                                             \
      g1[i] = ok ? rp[65536] : 0.f;                                         \
      g2[i] = ok ? rp[131072] : 0.f;                                        \
    }                                                                       \
  }

#define STAGE_WRITE(BUF)                                                    \
  {                                                                         \
    _Pragma("unroll")                                                       \
    for (int i = 0; i < 3; i++) {                                           \
      if (pokS[i]) {                                                        \
        h4 pk;                                                              \
        pk[0] = (f16)g0[i]; pk[1] = (f16)g1[i];                             \
        pk[2] = (f16)g2[i]; pk[3] = (f16)0.f;                               \
        *(h4*)(&sImgF[BUF][rS[i]][colS[i]][0]) = pk;                        \
      }                                                                     \
    }                                                                       \
  }

__global__ __launch_bounds__(256, 4) void conv12_m(const float* __restrict__ img_t,
    const float* __restrict__ img_t1,
    const f16* __restrict__ wT1, const float* __restrict__ b1,
    const f16* __restrict__ wT2, const float* __restrict__ b2, f16* __restrict__ out)
{
  const int ohc = blockIdx.x, g = blockIdx.y, bb = blockIdx.z;
  const int tid = threadIdx.x;
  const int lane = tid & 63, wv = tid >> 6;
  const int n15 = lane & 15, quad = lane >> 4;

  __shared__ f16 sImgF[2][5][134][4];
  __shared__ f16 sA[3 * 132 * 40];

  const int OW0 = g * 64;
  const int ibase = 2 * OW0 - 2;
  const float* imgb = (bb < 32 ? img_t : img_t1) + (long)(bb & 31) * 3 * 65536;

  int colS[3], rS[3]; bool pokS[3];
  #pragma unroll
  for (int i = 0; i < 3; i++) {
    int p = tid + i * 256;
    pokS[i] = p < 670;
    int pc = pokS[i] ? p : 0;
    colS[i] = pc % 134; rS[i] = pc / 134;
  }

  v8h a0 = *(const v8h*)(wT1 + n15 * 32 + quad * 8);
  v8h a1 = *(const v8h*)(wT1 + (16 + n15) * 32 + quad * 8);
  v8h a2 = *(const v8h*)(wT1 + (32 + n15) * 32 + quad * 8);
  v8h a3 = *(const v8h*)(wT1 + (48 + n15) * 32 + quad * 8);
  float4 bb0 = *(const float4*)(b1 + quad * 4);
  float4 bb1 = *(const float4*)(b1 + 16 + quad * 4);

  float g0[3], g1[3], g2[3];
  const int oh0 = ohc * 8;

  STAGE_ISSUE(oh0);
  STAGE_WRITE(0);

  for (int it = 0; it < 8; it++) {
    const int oh = oh0 + it;
    const int cur = it & 1;
    if (it < 7) STAGE_ISSUE(oh + 1);
    __syncthreads();

    for (int grp = wv; grp < 25; grp += 4) {
      int p = grp * 16 + n15;
      bool pv = p < 387;
      int pc = pv ? p : 386;
      int yr = pc >= 258 ? 2 : (pc >= 129 ? 1 : 0);
      int ci = pc - yr * 129;
      const f16* sp = &sImgF[cur][yr][ci][0] + quad;
      v8h B1;
      #pragma unroll
      for (int j = 0; j < 8; j++)
        B1[j] = sp[(j / 3) * 536 + (j % 3) * 4];
      h4 t = *(const h4*)(&sImgF[cur][yr + 2][ci + 2][0]);
      v8h B2;
      B2[0] = t[0]; B2[1] = t[1]; B2[2] = t[2]; B2[3] = t[3];
      B2[4] = t[0]; B2[5] = t[1]; B2[6] = t[2]; B2[7] = t[3];
      v4f acc0 = {}, acc1 = {};
      acc0 = __builtin_amdgcn_mfma_f32_16x16x32_f16(a0, B1, acc0, 0, 0, 0);
      acc1 = __builtin_amdgcn_mfma_f32_16x16x32_f16(a1, B1, acc1, 0, 0, 0);
      acc0 = __builtin_amdgcn_mfma_f32_16x16x32_f16(a2, B2, acc0, 0, 0, 0);
      acc1 = __builtin_amdgcn_mfma_f32_16x16x32_f16(a3, B2, acc1, 0, 0, 0);
      int y = 2 * oh - 1 + yr;
      int iw = ibase + 1 + ci;
      bool valid = pv && ((unsigned)y < 256u) && ((unsigned)iw < 256u);
      f16* base = &sA[(yr * 132 + ci) * 40];
      h4 pk0, pk1;
      #pragma unroll
      for (int r = 0; r < 4; r++) {
        float v0 = acc0[r] + ((const float*)&bb0)[r];
        float v1 = acc1[r] + ((const float*)&bb1)[r];
        pk0[r] = (f16)((valid && v0 > 0.f) ? v0 : 0.f);
        pk1[r] = (f16)((valid && v1 > 0.f) ? v1 : 0.f);
      }
      if (pv) {
        *(h4*)(base + quad * 4) = pk0;
        *(h4*)(base + 16 + quad * 4) = pk1;
      }
    }
    __syncthreads();

    v4f acc[4] = {};
    for (int kh = 0; kh < 3; kh++) {
      for (int kw = 0; kw < 3; kw++) {
        int khkw = kh * 3 + kw;
        const f16* wp = wT2 + khkw * 2048 + n15 * 32 + quad * 8;
        v8h w0 = *(const v8h*)(wp);
        v8h w1v = *(const v8h*)(wp + 512);
        v8h w2v = *(const v8h*)(wp + 1024);
        v8h w3v = *(const v8h*)(wp + 1536);
        int ci = 32 * wv + 2 * n15 + kw;
        v8h bf = *(const v8h*)&sA[(kh * 132 + ci) * 40 + quad * 8];
        acc[0] = __builtin_amdgcn_mfma_f32_16x16x32_f16(w0, bf, acc[0], 0, 0, 0);
        acc[1] = __builtin_amdgcn_mfma_f32_16x16x32_f16(w1v, bf, acc[1], 0, 0, 0);
        acc[2] = __builtin_amdgcn_mfma_f32_16x16x32_f16(w2v, bf, acc[2], 0, 0, 0);
        acc[3] = __builtin_amdgcn_mfma_f32_16x16x32_f16(w3v, bf, acc[3], 0, 0, 0);
      }
    }
    const int ow = OW0 + wv * 16 + n15;
    #pragma unroll
    for (int mt = 0; mt < 4; mt++) {
      int oc0 = mt * 16 + quad * 4;
      float4 bbv = *(const float4*)(b2 + oc0);
      h4 pk;
      #pragma unroll
      for (int r = 0; r < 4; r++) {
        float v = acc[mt][r] + ((const float*)&bbv)[r];
        pk[r] = (f16)(v > 0.f ? v : 0.f);
      }
      *(h4*)(out + (((long)(bb * 128 + oh) * 128 + ow) * 64) + oc0) = pk;
    }

    if (it < 7) STAGE_WRITE(cur ^ 1);
  }
}

// ---------------- conv3 v3: persistent 16-oh, weights in LDS, T14 slab prefetch ----------------
// grid (4 ohc, 64 bb, 2 ocg); block 256 = 4 waves; wave wv covers ow [wv*16,+16), 64 oc.
// LDS: sW 18x64x(pitch 40) = 92KB (2-way-free A reads) + sIn 48KB = 138KB, 1 block/CU.
// Compute loop has ZERO global loads -> slab prefetch (only vmem) hides under MFMA;
// WRITE's vmcnt wait excludes younger stores.
#define ISSUE_SLAB(OH)                                                         \
  {                                                                            \
    int ih0_ = 2 * (OH) - 1;                                                   \
    _Pragma("unroll")                                                          \
    for (int i = 0; i < 12; i++) {                                             \
      int ih = ih0_ + rS3[i];                                                  \
      h8 v;                                                                    \
      _Pragma("unroll")                                                        \
      for (int e = 0; e < 8; e++) v[e] = (f16)0.f;                             \
      if ((unsigned)ih < 128u)                                                 \
        v = *(const h8*)(inb + ((long)(ih * 128 + iwS3[i])) * 64 + ckS3[i] * 8); \
      stg[i] = v;                                                              \
    }                                                                          \
  }

#define WRITE_SLAB()                                                           \
  {                                                                            \
    _Pragma("unroll")                                                          \
    for (int i = 0; i < 12; i++)                                               \
      *(h8*)(&sIn[(rS3[i] * 128 + iwS3[i]) * 64 + sckS3[i] * 8]) = stg[i];     \
  }

__global__ __launch_bounds__(256, 1) void conv3_m(const f16* __restrict__ in,
    const f16* __restrict__ wT, const float* __restrict__ b3,
    float* __restrict__ zbase, f16* __restrict__ nhbase)
{
  const int ohc = blockIdx.x, bb = blockIdx.y, ocg = blockIdx.z;
  const int ib = bb >> 5, b = bb & 31;
  const int tid = threadIdx.x;
  const int lane = tid & 63, wv = tid >> 6;
  const int n15 = lane & 15, quad = lane >> 4;
  const int ow = wv * 16 + n15;

  __shared__ f16 sW[18 * 64 * 40];
  __shared__ f16 sIn[3 * 128 * 64];

  const f16* inb = in + (long)bb * (128 * 128 * 64);

  // per-thread slab staging metadata (oh-invariant)
  int ckS3[12], iwS3[12], rS3[12], sckS3[12];
  #pragma unroll
  for (int i = 0; i < 12; i++) {
    int idx = tid + i * 256;
    ckS3[i] = idx & 7; iwS3[i] = (idx >> 3) & 127; rS3[i] = idx >> 10;
    sckS3[i] = ckS3[i] ^ ((iwS3[i] >> 1) & 7);
  }

  // ---- prologue: weights + first slab, T14 combined (one latency) ----
  h8 wstg[18];
  #pragma unroll
  for (int i = 0; i < 18; i++) {
    int idx = tid + i * 256;
    int kc = idx & 3, oc = (idx >> 2) & 63, ch = idx >> 8;
    wstg[i] = *(const h8*)(wT + ((long)(ch * 128 + ocg * 64 + oc) << 5) + kc * 8);
  }
  const int oh0 = ohc * 16;
  h8 stg[12];
  ISSUE_SLAB(oh0);
  #pragma unroll
  for (int i = 0; i < 18; i++) {
    int idx = tid + i * 256;
    int kc = idx & 3, oc = (idx >> 2) & 63, ch = idx >> 8;
    *(h8*)(&sW[(ch * 64 + oc) * 40 + kc * 8]) = wstg[i];
  }
  WRITE_SLAB();
  __syncthreads();

  const f16* swb = sW + n15 * 40 + quad * 8;
  float* zo = zbase + (long)ib * 16777216L;
  f16* nh = nhbase + (long)ib * 16777216L;

  for (int it = 0; it < 16; it++) {
    const int oh = oh0 + it;
    if (it < 15) ISSUE_SLAB(oh + 1);

    v4f acc[4] = {};
    for (int kh = 0; kh < 3; kh++) {
      #pragma unroll
      for (int kw = 0; kw < 3; kw++) {
        int iw = 2 * ow + kw - 1;
        bool bok = (unsigned)iw < 128u;
        int iwc = bok ? iw : 0;
        #pragma unroll
        for (int ich = 0; ich < 2; ich++) {
          int ch = (kh * 3 + kw) * 2 + ich;
          int ck = ich * 4 + quad;
          int sck = ck ^ ((iwc >> 1) & 7);
          v8h bf;
          #pragma unroll
          for (int e = 0; e < 8; e++) bf[e] = (f16)0.f;
          if (bok) bf = *(const v8h*)&sIn[(kh * 128 + iwc) * 64 + sck * 8];
          const f16* wp = swb + ch * (64 * 40);
          #pragma unroll
          for (int mt = 0; mt < 4; mt++) {
            v8h a = *(const v8h*)(wp + mt * (16 * 40));
            acc[mt] = __builtin_amdgcn_mfma_f32_16x16x32_f16(a, bf, acc[mt], 0, 0, 0);
          }
        }
      }
    }

    #pragma unroll
    for (int mt = 0; mt < 4; mt++) {
      int oc0 = ocg * 64 + mt * 16 + quad * 4;
      float4 bbv = *(const float4*)(b3 + oc0);
      float rv[4];
      #pragma unroll
      for (int r = 0; r < 4; r++) {
        float v = acc[mt][r] + ((const float*)&bbv)[r];
        rv[r] = v > 0.f ? v : 0.f;
      }
      #pragma unroll
      for (int r = 0; r < 4; r++)
        zo[(((long)(b * 128 + oc0 + r) * 64 + oh) * 64) + ow] = rv[r];
      h4 pk;
      #pragma unroll
      for (int r = 0; r < 4; r++) pk[r] = (f16)rv[r];
      *(h4*)(nh + (((long)(b * 64 + oh) * 64 + ow) * 128) + oc0) = pk;
    }

    __syncthreads();              // all waves done reading sIn
    if (it < 15) {
      WRITE_SLAB();               // waits only the 12 slab loads (stores younger)
      __syncthreads();
    }
  }
}

// ---------------- local correlation via MFMA: K=13, C=128 ----------------
__global__ __launch_bounds__(256) void corr_m(const f16* __restrict__ zt,
    const f16* __restrict__ zt1, float* __restrict__ corr, float* __restrict__ part)
{
  const int h = blockIdx.x, b = blockIdx.y;
  const int lane = threadIdx.x & 63, wv = threadIdx.x >> 6;
  const int n15 = lane & 15, quad = lane >> 4;
  const int w0 = wv * 16;
  __shared__ float sC[64][17];

  const f16* arow = zt + (((long)(b * 64 + h) * 64 + (w0 + n15)) * 128) + quad * 8;
  v8h A[4];
  #pragma unroll
  for (int ks = 0; ks < 4; ks++) A[ks] = *(const v8h*)(arow + ks * 32);

  float* cb = corr + (long)b * 169 * 4096 + h * 64;

  const int q4r0 = quad * 4;
  const int wq0 = w0 - 6 + n15;
  const int wq1 = w0 + 10 + n15;
  const bool ok0 = (unsigned)wq0 < 64u;
  const bool ok1 = (unsigned)wq1 < 64u;

  for (int ki = 0; ki < 13; ki++) {
    int row = h + ki - 6;
    bool rok = (unsigned)row < 64u;
    v4f acc0 = {}, acc1 = {};
    if (rok) {
      const f16* brow = zt1 + ((long)(b * 64 + row) * 64) * 128;
      const f16* bp0 = brow + (long)wq0 * 128 + quad * 8;
      const f16* bp1 = brow + (long)wq1 * 128 + quad * 8;
      #pragma unroll
      for (int ks = 0; ks < 4; ks++) {
        v8h b0, b1;
        #pragma unroll
        for (int k = 0; k < 8; k++) { b0[k] = (f16)0.f; b1[k] = (f16)0.f; }
        if (ok0) b0 = *(const v8h*)(bp0 + ks * 32);
        if (ok1) b1 = *(const v8h*)(bp1 + ks * 32);
        acc0 = __builtin_amdgcn_mfma_f32_16x16x32_f16(A[ks], b0, acc0, 0, 0, 0);
        acc1 = __builtin_amdgcn_mfma_f32_16x16x32_f16(A[ks], b1, acc1, 0, 0, 0);
      }
    }
    __syncthreads();
    #pragma unroll
    for (int r = 0; r < 4; r++) {
      int q4r = q4r0 + r;
      int w = w0 + q4r;
      int kj0 = n15 - q4r;
      if (kj0 >= 0 && kj0 < 13) sC[w][kj0] = acc0[r] * INV_SQRT_C;
      int kj1 = kj0 + 16;
      if (kj1 < 13) sC[w][kj1] = acc1[r] * INV_SQRT_C;
    }
    __syncthreads();
    for (int idx = threadIdx.x; idx < 832; idx += 256) {
      int w = idx & 63, kj = idx >> 6;
      float v = sC[w][kj];
      cb[(long)(ki * 13 + kj) * 4096 + w] = v;
      #pragma unroll
      for (int off = 32; off > 0; off >>= 1) v += __shfl_down(v, off, 64);
      if (lane == 0) part[(long)(ki * 13 + kj) * 2048 + b * 64 + h] = v;
    }
  }
}

// ---------------- h_t: reduce partial row sums over h ----------------
__global__ __launch_bounds__(256) void ht2_k(const float* __restrict__ part,
                                             float* __restrict__ ht)
{
  int o = blockIdx.x;
  int t = threadIdx.x;
  int b = t >> 3, s = t & 7;
  const float* p = part + (long)o * 2048 + b * 64 + s * 8;
  float v = 0.f;
  #pragma unroll
  for (int i = 0; i < 8; i++) v += p[i];
  #pragma unroll
  for (int off = 4; off > 0; off >>= 1) v += __shfl_down(v, off, 8);
  if (s == 0) ht[b * 169 + o] = v * (1.f / 4096.f);
}

// ---------------- pred ----------------
__global__ void pred_k(const float* __restrict__ ht, const float* __restrict__ wh,
                       const float* __restrict__ bh, float* __restrict__ pred)
{
  int t = threadIdx.x;
  int b = t >> 1, j = t & 1;
  float s = bh[j];
  for (int o = 0; o < 169; o++) s = fmaf(ht[b * 169 + o], wh[j * 169 + o], s);
  pred[b * 2 + j] = s;
}

extern "C" void kernel_launch(void* const* d_in, const int* in_sizes, int n_in,
                              void* d_out, int out_size, void* d_ws, size_t ws_size,
                              hipStream_t stream)
{
  (void)in_sizes; (void)n_in; (void)out_size; (void)ws_size;
  const float* img_t  = (const float*)d_in[0];
  const float* img_t1 = (const float*)d_in[1];
  const float* w1 = (const float*)d_in[2];
  const float* b1 = (const float*)d_in[3];
  const float* w2 = (const float*)d_in[4];
  const float* b2 = (const float*)d_in[5];
  const float* w3 = (const float*)d_in[6];
  const float* b3 = (const float*)d_in[7];
  const float* wh = (const float*)d_in[8];
  const float* bh = (const float*)d_in[9];
  float* out = (float*)d_out;

  // workspace layout
  char* ws = (char*)d_ws;
  f16* bufB = (f16*)ws;                       // conv2 out NHWC, both imgs: 128 MiB
  f16* nhT  = (f16*)(ws + 134217728L);        // z_t NHWC fp16: 32 MiB (z_t1 contiguous after)
  float* part = (float*)(ws + 201326592L);    // 1.38 MiB

  const long OUT_ZT   = 64;
  const long OUT_ZT1  = OUT_ZT + 16777216L;
  const long OUT_CORR = OUT_ZT1 + 16777216L;
  const long OUT_HT   = OUT_CORR + 22151168L;

  // transposed weights live in the (not-yet-written) corr region of d_out;
  // corr_m fully overwrites this region afterwards.
  f16* wT1 = (f16*)(out + OUT_CORR);          // 2048  f16
  f16* wT2 = wT1 + 2048;                      // 18432 f16
  f16* wT3 = wT2 + 18432;                     // 73728 f16

  wt1_k<<<8, 256, 0, stream>>>(w1, wT1);
  wt2_k<<<72, 256, 0, stream>>>(w2, wT2);
  wt3_k<<<288, 256, 0, stream>>>(w3, wT3);

  conv12_m<<<dim3(16, 2, 64), 256, 0, stream>>>(img_t, img_t1, wT1, b1, wT2, b2, bufB);
  conv3_m<<<dim3(4, 64, 2), 256, 0, stream>>>(bufB, wT3, b3, out + OUT_ZT, nhT);
  corr_m<<<dim3(64, 32), 256, 0, stream>>>(nhT, nhT + 16777216L, out + OUT_CORR, part);
  ht2_k<<<169, 256, 0, stream>>>(part, out + OUT_HT);
  pred_k<<<1, 64, 0, stream>>>(out + OUT_HT, wh, bh, out);
}